// Round 4
// baseline (244.662 us; speedup 1.0000x reference)
//
#include <hip/hip_runtime.h>
#include <hip/hip_bf16.h>

#define D_MODEL 512
#define NHEAD   8
#define DK      64
#define SEQ     4096
#define BATCH   2
#define NTOK    (BATCH * SEQ)

typedef __bf16 bf16;
typedef __bf16 bf16x2 __attribute__((ext_vector_type(2)));
typedef __bf16 bf16x4 __attribute__((ext_vector_type(4)));
typedef __bf16 bf16x8 __attribute__((ext_vector_type(8)));
typedef float  f32x4  __attribute__((ext_vector_type(4)));
typedef float  f32x16 __attribute__((ext_vector_type(16)));
typedef unsigned u32x4 __attribute__((ext_vector_type(4)));

#define MFMA16(a, b, c) __builtin_amdgcn_mfma_f32_16x16x32_bf16((a), (b), (c), 0, 0, 0)
#define MFMA32(a, b, c) __builtin_amdgcn_mfma_f32_32x32x16_bf16((a), (b), (c), 0, 0, 0)

// 0.125 (1/sqrt(dk)) * log2(e) folded into Q so softmax is exp2(s) directly.
#define QSCALE 0.18033688f

// Plain-cast packed bf16 pair (compiler lowers to v_cvt_pk_bf16_f32).
__device__ __forceinline__ unsigned pkbf16(float a, float b) {
    bf16x2 t = {(bf16)a, (bf16)b};
    return __builtin_bit_cast(unsigned, t);
}

// ---------------------------------------------------------------------------
// Kernel 1: fused QKV projection, 128x128 tile, BK=64.
// p = 0:Q (pre-scaled by QSCALE), 1:K, 2:V.  W read DIRECTLY as fp32 and
// converted during LDS staging (cvt_w kernel + Wb round-trip eliminated;
// W is L3-resident so the 2x fp32 bytes are cache hits).
// V goes through an LDS transpose so the Vt[bh][d][s] store is coalesced.
// ---------------------------------------------------------------------------
__global__ __launch_bounds__(256, 3) void proj_qkv(
    const float* __restrict__ q, const float* __restrict__ k, const float* __restrict__ v,
    const float* __restrict__ wq, const float* __restrict__ wk, const float* __restrict__ wv,
    const float* __restrict__ bq, const float* __restrict__ bk, const float* __restrict__ bv,
    bf16* __restrict__ Qh, bf16* __restrict__ Kh, bf16* __restrict__ Vt)
{
    const int p = blockIdx.z;
    const float* X    = (p == 0) ? q  : (p == 1) ? k  : v;
    const float* W    = (p == 0) ? wq : (p == 1) ? wk : wv;
    const float* bias = (p == 0) ? bq : (p == 1) ? bk : bv;

    __shared__ union __align__(16) {
        struct { bf16 As[128][72]; bf16 Bs[128][72]; } g;
        bf16 T[128][136];   // V-transpose buffer
    } sm;

    const int m0   = blockIdx.x * 128;
    const int n0   = blockIdx.y * 128;
    const int tid  = threadIdx.x;
    const int lane = tid & 63;
    const int wave = tid >> 6;
    const int low4 = lane & 15;
    const int quad = lane >> 4;
    const int wm   = wave >> 1;
    const int wn   = wave & 1;

    int srow[8], sc4[8];
    for (int it = 0; it < 8; ++it) {
        int idx = tid + it * 256;          // 0..2047
        srow[it] = idx >> 4;               // 0..127
        sc4[it]  = (idx & 15) * 4;         // 0..60
    }
    int br[4], bc[4];
    for (int it = 0; it < 4; ++it) {
        int idx = tid + it * 256;          // 0..1023
        br[it] = idx >> 3;                 // 0..127
        bc[it] = (idx & 7) * 8;            // 0..56
    }

    float4 gA[8];
    float4 gB0[4], gB1[4];
    for (int it = 0; it < 8; ++it)
        gA[it] = *(const float4*)(X + (size_t)(m0 + srow[it]) * D_MODEL + sc4[it]);
    for (int it = 0; it < 4; ++it) {
        const float* src = W + (size_t)(n0 + br[it]) * D_MODEL + bc[it];
        gB0[it] = *(const float4*)src;
        gB1[it] = *(const float4*)(src + 4);
    }

    f32x4 acc[4][4];
    for (int i = 0; i < 4; ++i)
        for (int j = 0; j < 4; ++j)
            acc[i][j] = f32x4{0.f, 0.f, 0.f, 0.f};

    for (int k0 = 0; k0 < D_MODEL; k0 += 64) {
        __syncthreads();
        for (int it = 0; it < 8; ++it) {
            bf16x4 wa = {(bf16)gA[it].x, (bf16)gA[it].y, (bf16)gA[it].z, (bf16)gA[it].w};
            *(bf16x4*)&sm.g.As[srow[it]][sc4[it]] = wa;
        }
        for (int it = 0; it < 4; ++it) {
            bf16x8 wb = {(bf16)gB0[it].x, (bf16)gB0[it].y, (bf16)gB0[it].z, (bf16)gB0[it].w,
                         (bf16)gB1[it].x, (bf16)gB1[it].y, (bf16)gB1[it].z, (bf16)gB1[it].w};
            *(bf16x8*)&sm.g.Bs[br[it]][bc[it]] = wb;
        }
        __syncthreads();

        if (k0 + 64 < D_MODEL) {
            for (int it = 0; it < 8; ++it)
                gA[it] = *(const float4*)(X + (size_t)(m0 + srow[it]) * D_MODEL + k0 + 64 + sc4[it]);
            for (int it = 0; it < 4; ++it) {
                const float* src = W + (size_t)(n0 + br[it]) * D_MODEL + k0 + 64 + bc[it];
                gB0[it] = *(const float4*)src;
                gB1[it] = *(const float4*)(src + 4);
            }
        }

        for (int ks = 0; ks < 2; ++ks) {
            bf16x8 a[4], b[4];
            for (int i = 0; i < 4; ++i)
                a[i] = *(const bf16x8*)&sm.g.As[wm * 64 + i * 16 + low4][ks * 32 + quad * 8];
            for (int j = 0; j < 4; ++j)
                b[j] = *(const bf16x8*)&sm.g.Bs[wn * 64 + j * 16 + low4][ks * 32 + quad * 8];
            for (int i = 0; i < 4; ++i)
                for (int j = 0; j < 4; ++j)
                    acc[i][j] = MFMA16(a[i], b[j], acc[i][j]);
        }
    }

    if (p < 2) {
        bf16* Out = (p == 0) ? Qh : Kh;
        const float sc = (p == 0) ? QSCALE : 1.0f;
        for (int j = 0; j < 4; ++j) {
            int col = n0 + wn * 64 + j * 16 + low4;
            float bcol = bias[col];
            for (int i = 0; i < 4; ++i)
                for (int r = 0; r < 4; ++r) {
                    int row = m0 + wm * 64 + i * 16 + quad * 4 + r;
                    Out[(size_t)row * D_MODEL + col] = (bf16)((acc[i][j][r] + bcol) * sc);
                }
        }
    } else {
        // V: transpose through LDS -> coalesced b128 stores to Vt[bh][d][s].
        __syncthreads();
        for (int j = 0; j < 4; ++j) {
            int col = n0 + wn * 64 + j * 16 + low4;
            float bcol = bias[col];
            for (int i = 0; i < 4; ++i)
                for (int r = 0; r < 4; ++r)
                    sm.T[wn * 64 + j * 16 + low4][wm * 64 + i * 16 + quad * 4 + r] =
                        (bf16)(acc[i][j][r] + bcol);
        }
        __syncthreads();
        const int bb = m0 >> 12;
        const int s0 = (m0 & 4095);
        for (int it = 0; it < 8; ++it) {
            int cc = it * 16 + (tid >> 4);   // 0..127 col-local
            int ml = (tid & 15) * 8;         // 0..120 m-local
            int col = n0 + cc;
            int hh = col >> 6, dd = col & 63;
            *(bf16x8*)&Vt[(((size_t)(bb * NHEAD + hh) * DK + dd) << 12) + s0 + ml] =
                *(const bf16x8*)&sm.T[cc][ml];
        }
    }
}

// ---------------------------------------------------------------------------
// Kernel 2: flash attention, 32x32x16 MFMA, 512 thr = 4 q-groups x 2 key-halves.
// Round-4: round-0 PHASE ORDERING restored (both mt QK+softmax first, then
// the full 8-MFMA PV pass) with P held in registers (pf00..pf11) instead of
// the Ps LDS round-trip.  QK(mt1)'s MFMA cluster overlaps mt0's exp chain
// (separate pipes) -- the ILP round 3 lost.  Padded Ks/Vs, two barriers,
// no swizzle, no setprio (all shown neutral/harmful in rounds 1-3).
// Layouts (m74/m101-verified C/D; A/B by the same half-wave pattern):
//   A[m=lane&31][k=(lane>>5)*8+j]  B[n=lane&31][k=(lane>>5)*8+j]
//   C/D: col=lane&31, row=(reg&3)+8*(reg>>2)+4*(lane>>5)
// ---------------------------------------------------------------------------
__global__ __launch_bounds__(512, 2) void attn(
    const bf16* __restrict__ Qh, const bf16* __restrict__ Kh,
    const bf16* __restrict__ Vt, bf16* __restrict__ O)
{
    __shared__ union __align__(16) {
        struct { bf16 Ks[128][72]; bf16 Vs[64][136]; } s;
        float Obuf[4][32][68];               // kg-combine buffer (overlays Ks/Vs)
    } sm;
    __shared__ float Lbuf[4][32];

    const int q0   = blockIdx.x * 128;
    const int bh   = blockIdx.y;
    const int b    = bh >> 3, h = bh & 7;
    const int tid  = threadIdx.x;
    const int lane = tid & 63;
    const int wave = tid >> 6;      // 0..7
    const int qg   = wave >> 1;     // 0..3 : q-group (32 rows)
    const int kg   = wave & 1;      // 0..1 : key half
    const int m32  = lane & 31;
    const int hl   = lane >> 5;     // 0..1

    const bf16* Kbase = Kh + (size_t)b * SEQ * D_MODEL + h * DK;
    const bf16* Vbase = Vt + (size_t)bh * DK * SEQ;

    // Q B-frags, resident all kernel: qf[ks] covers k = ks*16 + hl*8 .. +7
    const bf16* Qrow = Qh + (size_t)(b * SEQ + q0 + qg * 32 + m32) * D_MODEL + h * DK;
    bf16x8 qf[4];
    for (int ks = 0; ks < 4; ++ks)
        qf[ks] = *(const bf16x8*)(Qrow + ks * 16 + hl * 8);

    float l = 0.f;
    f32x16 acc[2];
    for (int i = 0; i < 16; ++i) { acc[0][i] = 0.f; acc[1][i] = 0.f; }

    int kr[2], kc[2], vr[2], vc[2];
    for (int it = 0; it < 2; ++it) {
        int c = tid + it * 512;      // 0..1023
        kr[it] = c >> 3;  kc[it] = (c & 7) * 8;    // Ks: 128 rows x 64 d
        vr[it] = c >> 4;  vc[it] = (c & 15) * 8;   // Vs: 64 rows x 128 t
    }
    bf16x8 gk[2], gv[2];
    for (int it = 0; it < 2; ++it) {
        gk[it] = *(const bf16x8*)(Kbase + (size_t)kr[it] * D_MODEL + kc[it]);
        gv[it] = *(const bf16x8*)(Vbase + (size_t)vr[it] * SEQ + vc[it]);
    }

    for (int t0 = 0; t0 < SEQ; t0 += 128) {
        __syncthreads();
        for (int it = 0; it < 2; ++it) {
            *(bf16x8*)&sm.s.Ks[kr[it]][kc[it]] = gk[it];
            *(bf16x8*)&sm.s.Vs[vr[it]][vc[it]] = gv[it];
        }
        __syncthreads();

        if (t0 + 128 < SEQ) {
            for (int it = 0; it < 2; ++it) {
                gk[it] = *(const bf16x8*)(Kbase + (size_t)(t0 + 128 + kr[it]) * D_MODEL + kc[it]);
                gv[it] = *(const bf16x8*)(Vbase + (size_t)vr[it] * SEQ + t0 + 128 + vc[it]);
            }
        }

        // ---- both 32-key tiles: S^T = K Q^T, exp, pack -> P frags in regs ----
        u32x4 pf00, pf01, pf10, pf11;    // [mt][half]: named, static indexing only
        for (int mt = 0; mt < 2; ++mt) {
            f32x16 sc;
            for (int i = 0; i < 16; ++i) sc[i] = 0.f;
            for (int ks = 0; ks < 4; ++ks) {
                bf16x8 kf = *(const bf16x8*)&sm.s.Ks[kg * 64 + mt * 32 + m32][ks * 16 + hl * 8];
                sc = MFMA32(kf, qf[ks], sc);
            }

            // sc[4g+i] holds key tk = i + 8g + 4hl (tile-local), q = m32.
            // pa covers tile keys hl*8+{0..7}, pb covers 16+hl*8+{0..7}.
            u32x4 pa, pb;
            {
                float p0 = __builtin_amdgcn_exp2f(sc[0]);
                float p1 = __builtin_amdgcn_exp2f(sc[1]);
                float p2 = __builtin_amdgcn_exp2f(sc[2]);
                float p3 = __builtin_amdgcn_exp2f(sc[3]);
                l += (p0 + p1) + (p2 + p3);
                unsigned y0 = pkbf16(p0, p1), y1 = pkbf16(p2, p3);
                p0 = __builtin_amdgcn_exp2f(sc[4]);
                p1 = __builtin_amdgcn_exp2f(sc[5]);
                p2 = __builtin_amdgcn_exp2f(sc[6]);
                p3 = __builtin_amdgcn_exp2f(sc[7]);
                l += (p0 + p1) + (p2 + p3);
                unsigned y2 = pkbf16(p0, p1), y3 = pkbf16(p2, p3);
                auto s0 = __builtin_amdgcn_permlane32_swap(y0, y2, false, false);
                auto s1 = __builtin_amdgcn_permlane32_swap(y1, y3, false, false);
                pa[0] = s0[0]; pa[2] = s0[1]; pa[1] = s1[0]; pa[3] = s1[1];

                p0 = __builtin_amdgcn_exp2f(sc[8]);
                p1 = __builtin_amdgcn_exp2f(sc[9]);
                p2 = __builtin_amdgcn_exp2f(sc[10]);
                p3 = __builtin_amdgcn_exp2f(sc[11]);
                l += (p0 + p1) + (p2 + p3);
                y0 = pkbf16(p0, p1); y1 = pkbf16(p2, p3);
                p0 = __builtin_amdgcn_exp2f(sc[12]);
                p1 = __builtin_amdgcn_exp2f(sc[13]);
                p2 = __builtin_amdgcn_exp2f(sc[14]);
                p3 = __builtin_amdgcn_exp2f(sc[15]);
                l += (p0 + p1) + (p2 + p3);
                y2 = pkbf16(p0, p1); y3 = pkbf16(p2, p3);
                auto s2 = __builtin_amdgcn_permlane32_swap(y0, y2, false, false);
                auto s3 = __builtin_amdgcn_permlane32_swap(y1, y3, false, false);
                pb[0] = s2[0]; pb[2] = s2[1]; pb[1] = s3[0]; pb[3] = s3[1];
            }
            if (mt == 0) { pf00 = pa; pf01 = pb; }
            else         { pf10 = pa; pf11 = pb; }
        }

        // ---- O += P V over all 64 local keys (global ks = 0..3) ----
        {
            bf16x8 p0 = __builtin_bit_cast(bf16x8, pf00);
            bf16x8 p1 = __builtin_bit_cast(bf16x8, pf01);
            bf16x8 p2 = __builtin_bit_cast(bf16x8, pf10);
            bf16x8 p3 = __builtin_bit_cast(bf16x8, pf11);
            for (int nt = 0; nt < 2; ++nt) {
                bf16x8 v0 = *(const bf16x8*)&sm.s.Vs[nt * 32 + m32][kg * 64 + 0 * 16 + hl * 8];
                acc[nt] = MFMA32(p0, v0, acc[nt]);
            }
            for (int nt = 0; nt < 2; ++nt) {
                bf16x8 v1 = *(const bf16x8*)&sm.s.Vs[nt * 32 + m32][kg * 64 + 1 * 16 + hl * 8];
                acc[nt] = MFMA32(p1, v1, acc[nt]);
            }
            for (int nt = 0; nt < 2; ++nt) {
                bf16x8 v2 = *(const bf16x8*)&sm.s.Vs[nt * 32 + m32][kg * 64 + 2 * 16 + hl * 8];
                acc[nt] = MFMA32(p2, v2, acc[nt]);
            }
            for (int nt = 0; nt < 2; ++nt) {
                bf16x8 v3 = *(const bf16x8*)&sm.s.Vs[nt * 32 + m32][kg * 64 + 3 * 16 + hl * 8];
                acc[nt] = MFMA32(p3, v3, acc[nt]);
            }
        }
    }

    // ---- combine key-halves + normalize + store ----
    l += __shfl_xor(l, 32);                  // full sum over this wave's 64 keys
    __syncthreads();                         // Ks/Vs dead -> Obuf overlay safe
    if (kg == 1) {
        for (int nt = 0; nt < 2; ++nt)
            for (int r = 0; r < 16; ++r) {
                int qq = (r & 3) + 8 * (r >> 2) + 4 * hl;
                sm.Obuf[qg][qq][nt * 32 + m32] = acc[nt][r];
            }
        if (hl == 0) Lbuf[qg][m32] = l;
    }
    __syncthreads();
    if (kg == 0) {
        float lt  = l + Lbuf[qg][m32];
        float inv = 1.0f / lt;               // valid for q = m32
        for (int nt = 0; nt < 2; ++nt)
            for (int r = 0; r < 16; ++r) {
                int qq = (r & 3) + 8 * (r >> 2) + 4 * hl;
                float val = acc[nt][r] + sm.Obuf[qg][qq][nt * 32 + m32];
                float iv  = __shfl(inv, qq);
                O[(size_t)(b * SEQ + q0 + qg * 32 + qq) * D_MODEL + h * DK + nt * 32 + m32] =
                    (bf16)(val * iv);
            }
    }
}

// ---------------------------------------------------------------------------
// Kernel 3: output projection, 64x64 tile (1024 blocks -> 4/CU).
// Wo read directly as fp32, converted during staging (Wb eliminated).
// ---------------------------------------------------------------------------
__global__ __launch_bounds__(256, 4) void proj_out(
    const bf16* __restrict__ Oin, const float* __restrict__ Wo,
    const float* __restrict__ bo, float* __restrict__ out)
{
    __shared__ bf16 As[64][72];
    __shared__ bf16 Bs[64][72];

    const int m0   = blockIdx.x * 64;
    const int n0   = blockIdx.y * 64;
    const int tid  = threadIdx.x;
    const int lane = tid & 63;
    const int wave = tid >> 6;
    const int low4 = lane & 15;
    const int quad = lane >> 4;
    const int wm   = wave >> 1;
    const int wn   = wave & 1;

    int arow[2], ag[2];
    for (int it = 0; it < 2; ++it) {
        int idx = tid + it * 256;
        arow[it] = idx >> 3;
        ag[it]   = (idx & 7) * 8;
    }

    bf16x8 gA[2];
    float4 gB0[2], gB1[2];
    for (int it = 0; it < 2; ++it) {
        gA[it] = *(const bf16x8*)(Oin + (size_t)(m0 + arow[it]) * D_MODEL + ag[it]);
        const float* src = Wo + (size_t)(n0 + arow[it]) * D_MODEL + ag[it];
        gB0[it] = *(const float4*)src;
        gB1[it] = *(const float4*)(src + 4);
    }

    f32x4 acc[2][2];
    for (int i = 0; i < 2; ++i)
        for (int j = 0; j < 2; ++j)
            acc[i][j] = f32x4{0.f, 0.f, 0.f, 0.f};

    for (int k0 = 0; k0 < D_MODEL; k0 += 64) {
        __syncthreads();
        for (int it = 0; it < 2; ++it) {
            *(bf16x8*)&As[arow[it]][ag[it]] = gA[it];
            bf16x8 wb = {(bf16)gB0[it].x, (bf16)gB0[it].y, (bf16)gB0[it].z, (bf16)gB0[it].w,
                         (bf16)gB1[it].x, (bf16)gB1[it].y, (bf16)gB1[it].z, (bf16)gB1[it].w};
            *(bf16x8*)&Bs[arow[it]][ag[it]] = wb;
        }
        __syncthreads();

        if (k0 + 64 < D_MODEL) {
            for (int it = 0; it < 2; ++it) {
                gA[it] = *(const bf16x8*)(Oin + (size_t)(m0 + arow[it]) * D_MODEL + k0 + 64 + ag[it]);
                const float* src = Wo + (size_t)(n0 + arow[it]) * D_MODEL + k0 + 64 + ag[it];
                gB0[it] = *(const float4*)src;
                gB1[it] = *(const float4*)(src + 4);
            }
        }

        for (int ks = 0; ks < 2; ++ks) {
            bf16x8 a[2], b[2];
            for (int i = 0; i < 2; ++i)
                a[i] = *(const bf16x8*)&As[wm * 32 + i * 16 + low4][ks * 32 + quad * 8];
            for (int j = 0; j < 2; ++j)
                b[j] = *(const bf16x8*)&Bs[wn * 32 + j * 16 + low4][ks * 32 + quad * 8];
            for (int i = 0; i < 2; ++i)
                for (int j = 0; j < 2; ++j)
                    acc[i][j] = MFMA16(a[i], b[j], acc[i][j]);
        }
    }

    for (int j = 0; j < 2; ++j) {
        int col = n0 + wn * 32 + j * 16 + low4;
        float bcol = bo[col];
        for (int i = 0; i < 2; ++i)
            for (int r = 0; r < 4; ++r) {
                int row = m0 + wm * 32 + i * 16 + quad * 4 + r;
                out[(size_t)row * D_MODEL + col] = acc[i][j][r] + bcol;
            }
    }
}

// ---------------------------------------------------------------------------
extern "C" void kernel_launch(void* const* d_in, const int* in_sizes, int n_in,
                              void* d_out, int out_size, void* d_ws, size_t ws_size,
                              hipStream_t stream)
{
    const float* q  = (const float*)d_in[0];
    const float* k  = (const float*)d_in[1];
    const float* v  = (const float*)d_in[2];
    const float* wq = (const float*)d_in[3];
    const float* bq = (const float*)d_in[4];
    const float* wk = (const float*)d_in[5];
    const float* bk = (const float*)d_in[6];
    const float* wv = (const float*)d_in[7];
    const float* bv = (const float*)d_in[8];
    const float* wo = (const float*)d_in[9];
    const float* bo = (const float*)d_in[10];

    const size_t NT = (size_t)NTOK * D_MODEL;
    bf16* Qh = (bf16*)d_ws;
    bf16* Kh = Qh + NT;
    bf16* Vt = Kh + NT;
    bf16* O  = Vt + NT;

    dim3 g1(NTOK / 128, D_MODEL / 128, 3);
    proj_qkv<<<g1, 256, 0, stream>>>(q, k, v, wq, wk, wv, bq, bk, bv, Qh, Kh, Vt);

    dim3 g2(SEQ / 128, BATCH * NHEAD);
    attn<<<g2, 512, 0, stream>>>(Qh, Kh, Vt, O);

    dim3 g3(NTOK / 64, D_MODEL / 64);
    proj_out<<<g3, 256, 0, stream>>>(O, wo, bo, (float*)d_out);
}

// Round 5
// 216.402 us; speedup vs baseline: 1.1306x; 1.1306x over previous
//
#include <hip/hip_runtime.h>
#include <hip/hip_bf16.h>

#define D_MODEL 512
#define NHEAD   8
#define DK      64
#define SEQ     4096
#define BATCH   2
#define NTOK    (BATCH * SEQ)

typedef __bf16 bf16;
typedef __bf16 bf16x2 __attribute__((ext_vector_type(2)));
typedef __bf16 bf16x4 __attribute__((ext_vector_type(4)));
typedef __bf16 bf16x8 __attribute__((ext_vector_type(8)));
typedef float  f32x4  __attribute__((ext_vector_type(4)));
typedef float  f32x16 __attribute__((ext_vector_type(16)));
typedef unsigned u32x4 __attribute__((ext_vector_type(4)));

#define MFMA16(a, b, c) __builtin_amdgcn_mfma_f32_16x16x32_bf16((a), (b), (c), 0, 0, 0)
#define MFMA32(a, b, c) __builtin_amdgcn_mfma_f32_32x32x16_bf16((a), (b), (c), 0, 0, 0)

// 0.125 (1/sqrt(dk)) * log2(e) folded into Q so softmax is exp2(s) directly.
#define QSCALE 0.18033688f

// Plain-cast packed bf16 pair (compiler lowers to v_cvt_pk_bf16_f32).
__device__ __forceinline__ unsigned pkbf16(float a, float b) {
    bf16x2 t = {(bf16)a, (bf16)b};
    return __builtin_bit_cast(unsigned, t);
}

// exp2 + pack + permlane transpose of one 32x32 S^T tile (verified r1-r4).
// sc[4g+i] holds key tk = i + 8g + 4hl (tile-local), q = m32.
// pa covers tile keys hl*8+{0..7}, pb covers 16+hl*8+{0..7} (A-frag layout).
__device__ __forceinline__ void softmax_pack(const f32x16& sc, float& l,
                                             u32x4& pa, u32x4& pb) {
    float p0 = __builtin_amdgcn_exp2f(sc[0]);
    float p1 = __builtin_amdgcn_exp2f(sc[1]);
    float p2 = __builtin_amdgcn_exp2f(sc[2]);
    float p3 = __builtin_amdgcn_exp2f(sc[3]);
    l += (p0 + p1) + (p2 + p3);
    unsigned y0 = pkbf16(p0, p1), y1 = pkbf16(p2, p3);
    p0 = __builtin_amdgcn_exp2f(sc[4]);
    p1 = __builtin_amdgcn_exp2f(sc[5]);
    p2 = __builtin_amdgcn_exp2f(sc[6]);
    p3 = __builtin_amdgcn_exp2f(sc[7]);
    l += (p0 + p1) + (p2 + p3);
    unsigned y2 = pkbf16(p0, p1), y3 = pkbf16(p2, p3);
    auto s0 = __builtin_amdgcn_permlane32_swap(y0, y2, false, false);
    auto s1 = __builtin_amdgcn_permlane32_swap(y1, y3, false, false);
    pa[0] = s0[0]; pa[2] = s0[1]; pa[1] = s1[0]; pa[3] = s1[1];

    p0 = __builtin_amdgcn_exp2f(sc[8]);
    p1 = __builtin_amdgcn_exp2f(sc[9]);
    p2 = __builtin_amdgcn_exp2f(sc[10]);
    p3 = __builtin_amdgcn_exp2f(sc[11]);
    l += (p0 + p1) + (p2 + p3);
    y0 = pkbf16(p0, p1); y1 = pkbf16(p2, p3);
    p0 = __builtin_amdgcn_exp2f(sc[12]);
    p1 = __builtin_amdgcn_exp2f(sc[13]);
    p2 = __builtin_amdgcn_exp2f(sc[14]);
    p3 = __builtin_amdgcn_exp2f(sc[15]);
    l += (p0 + p1) + (p2 + p3);
    y2 = pkbf16(p0, p1); y3 = pkbf16(p2, p3);
    auto s2 = __builtin_amdgcn_permlane32_swap(y0, y2, false, false);
    auto s3 = __builtin_amdgcn_permlane32_swap(y1, y3, false, false);
    pb[0] = s2[0]; pb[2] = s2[1]; pb[1] = s3[0]; pb[3] = s3[1];
}

// ---------------------------------------------------------------------------
// Kernel 0: weight fp32 -> bf16 (wq, wk, wv, wo), one float4 per thread.
// (Round-4's fp32-direct W staging regressed proj_qkv 90 -> 146 us; reverted.)
// ---------------------------------------------------------------------------
__global__ __launch_bounds__(256) void cvt_w(
    const float* __restrict__ wq, const float* __restrict__ wk,
    const float* __restrict__ wv, const float* __restrict__ wo,
    bf16* __restrict__ Wb)
{
    int i = blockIdx.x * 256 + threadIdx.x;          // 0..262143
    int m = i >> 16;                                 // matrix id
    int g = i & 65535;                               // float4 group
    const float* src = (m == 0) ? wq : (m == 1) ? wk : (m == 2) ? wv : wo;
    float4 x = *(const float4*)(src + (size_t)g * 4);
    bf16x4 y = {(bf16)x.x, (bf16)x.y, (bf16)x.z, (bf16)x.w};
    *(bf16x4*)(Wb + (size_t)m * D_MODEL * D_MODEL + (size_t)g * 4) = y;
}

// ---------------------------------------------------------------------------
// Kernel 1: fused QKV projection, 128x128 tile, BK=64.
// p = 0:Q (pre-scaled by QSCALE), 1:K, 2:V.  W read from pre-cvt bf16 Wb.
// V goes through an LDS transpose so the Vt[bh][d][s] store is coalesced.
// ---------------------------------------------------------------------------
__global__ __launch_bounds__(256, 3) void proj_qkv(
    const float* __restrict__ q, const float* __restrict__ k, const float* __restrict__ v,
    const bf16* __restrict__ Wb,
    const float* __restrict__ bq, const float* __restrict__ bk, const float* __restrict__ bv,
    bf16* __restrict__ Qh, bf16* __restrict__ Kh, bf16* __restrict__ Vt)
{
    const int p = blockIdx.z;
    const float* X    = (p == 0) ? q  : (p == 1) ? k  : v;
    const bf16*  W    = Wb + (size_t)p * D_MODEL * D_MODEL;
    const float* bias = (p == 0) ? bq : (p == 1) ? bk : bv;

    __shared__ union __align__(16) {
        struct { bf16 As[128][72]; bf16 Bs[128][72]; } g;
        bf16 T[128][136];   // V-transpose buffer
    } sm;

    const int m0   = blockIdx.x * 128;
    const int n0   = blockIdx.y * 128;
    const int tid  = threadIdx.x;
    const int lane = tid & 63;
    const int wave = tid >> 6;
    const int low4 = lane & 15;
    const int quad = lane >> 4;
    const int wm   = wave >> 1;
    const int wn   = wave & 1;

    int srow[8], sc4[8];
    for (int it = 0; it < 8; ++it) {
        int idx = tid + it * 256;          // 0..2047
        srow[it] = idx >> 4;               // 0..127
        sc4[it]  = (idx & 15) * 4;         // 0..60
    }
    int br[4], bc[4];
    for (int it = 0; it < 4; ++it) {
        int idx = tid + it * 256;          // 0..1023
        br[it] = idx >> 3;                 // 0..127
        bc[it] = (idx & 7) * 8;            // 0..56
    }

    float4 gA[8];
    bf16x8 gB[4];
    for (int it = 0; it < 8; ++it)
        gA[it] = *(const float4*)(X + (size_t)(m0 + srow[it]) * D_MODEL + sc4[it]);
    for (int it = 0; it < 4; ++it)
        gB[it] = *(const bf16x8*)(W + (size_t)(n0 + br[it]) * D_MODEL + bc[it]);

    f32x4 acc[4][4];
    for (int i = 0; i < 4; ++i)
        for (int j = 0; j < 4; ++j)
            acc[i][j] = f32x4{0.f, 0.f, 0.f, 0.f};

    for (int k0 = 0; k0 < D_MODEL; k0 += 64) {
        __syncthreads();
        for (int it = 0; it < 8; ++it) {
            bf16x4 wa = {(bf16)gA[it].x, (bf16)gA[it].y, (bf16)gA[it].z, (bf16)gA[it].w};
            *(bf16x4*)&sm.g.As[srow[it]][sc4[it]] = wa;
        }
        for (int it = 0; it < 4; ++it)
            *(bf16x8*)&sm.g.Bs[br[it]][bc[it]] = gB[it];
        __syncthreads();

        if (k0 + 64 < D_MODEL) {
            for (int it = 0; it < 8; ++it)
                gA[it] = *(const float4*)(X + (size_t)(m0 + srow[it]) * D_MODEL + k0 + 64 + sc4[it]);
            for (int it = 0; it < 4; ++it)
                gB[it] = *(const bf16x8*)(W + (size_t)(n0 + br[it]) * D_MODEL + k0 + 64 + bc[it]);
        }

        for (int ks = 0; ks < 2; ++ks) {
            bf16x8 a[4], b[4];
            for (int i = 0; i < 4; ++i)
                a[i] = *(const bf16x8*)&sm.g.As[wm * 64 + i * 16 + low4][ks * 32 + quad * 8];
            for (int j = 0; j < 4; ++j)
                b[j] = *(const bf16x8*)&sm.g.Bs[wn * 64 + j * 16 + low4][ks * 32 + quad * 8];
            for (int i = 0; i < 4; ++i)
                for (int j = 0; j < 4; ++j)
                    acc[i][j] = MFMA16(a[i], b[j], acc[i][j]);
        }
    }

    if (p < 2) {
        bf16* Out = (p == 0) ? Qh : Kh;
        const float sc = (p == 0) ? QSCALE : 1.0f;
        for (int j = 0; j < 4; ++j) {
            int col = n0 + wn * 64 + j * 16 + low4;
            float bcol = bias[col];
            for (int i = 0; i < 4; ++i)
                for (int r = 0; r < 4; ++r) {
                    int row = m0 + wm * 64 + i * 16 + quad * 4 + r;
                    Out[(size_t)row * D_MODEL + col] = (bf16)((acc[i][j][r] + bcol) * sc);
                }
        }
    } else {
        // V: transpose through LDS -> coalesced b128 stores to Vt[bh][d][s].
        __syncthreads();
        for (int j = 0; j < 4; ++j) {
            int col = n0 + wn * 64 + j * 16 + low4;
            float bcol = bias[col];
            for (int i = 0; i < 4; ++i)
                for (int r = 0; r < 4; ++r)
                    sm.T[wn * 64 + j * 16 + low4][wm * 64 + i * 16 + quad * 4 + r] =
                        (bf16)(acc[i][j][r] + bcol);
        }
        __syncthreads();
        const int bb = m0 >> 12;
        const int s0 = (m0 & 4095);
        for (int it = 0; it < 8; ++it) {
            int cc = it * 16 + (tid >> 4);   // 0..127 col-local
            int ml = (tid & 15) * 8;         // 0..120 m-local
            int col = n0 + cc;
            int hh = col >> 6, dd = col & 63;
            *(bf16x8*)&Vt[(((size_t)(bb * NHEAD + hh) * DK + dd) << 12) + s0 + ml] =
                *(const bf16x8*)&sm.T[cc][ml];
        }
    }
}

// ---------------------------------------------------------------------------
// Kernel 2: flash attention, 32x32x16 MFMA.
// Round-5: attn is LDS-BW-bound (288 b128 ops x 12cyc = 3456cyc/CU-phase ~=
// whole kernel).  Fix: 256 q-rows per block, 8 waves = 4 qg(64 rows = 2
// q-subtiles) x 2 kg.  Every kf/va LDS read now feeds TWO MFMAs -> LDS ops
// per MFMA halved; K/V tiles (and LDS size) unchanged; grid 256 blocks=1/CU.
// P kept fully in registers (pkbf16 + permlane32_swap, verified r1-r4).
// Layouts (m74/m101-verified C/D; A/B by the same half-wave pattern):
//   A[m=lane&31][k=(lane>>5)*8+j]  B[n=lane&31][k=(lane>>5)*8+j]
//   C/D: col=lane&31, row=(reg&3)+8*(reg>>2)+4*(lane>>5)
// ---------------------------------------------------------------------------
__global__ __launch_bounds__(512, 2) void attn(
    const bf16* __restrict__ Qh, const bf16* __restrict__ Kh,
    const bf16* __restrict__ Vt, bf16* __restrict__ O)
{
    __shared__ union __align__(16) {
        struct { bf16 Ks[128][72]; bf16 Vs[64][136]; } s;
        float Obuf[4][32][68];               // kg-combine buffer (overlays Ks/Vs)
    } sm;
    __shared__ float Lbuf[4][32];

    const int q0   = blockIdx.x * 256;
    const int bh   = blockIdx.y;
    const int b    = bh >> 3, h = bh & 7;
    const int tid  = threadIdx.x;
    const int lane = tid & 63;
    const int wave = tid >> 6;      // 0..7
    const int qg   = wave >> 1;     // 0..3 : q-group (64 rows = 2 subtiles)
    const int kg   = wave & 1;      // 0..1 : key half
    const int m32  = lane & 31;
    const int hl   = lane >> 5;     // 0..1

    const bf16* Kbase = Kh + (size_t)b * SEQ * D_MODEL + h * DK;
    const bf16* Vbase = Vt + (size_t)bh * DK * SEQ;

    // Q B-frags for both 32-row subtiles, resident all kernel.
    const bf16* Qrow0 = Qh + (size_t)(b * SEQ + q0 + qg * 64 + m32) * D_MODEL + h * DK;
    const bf16* Qrow1 = Qrow0 + (size_t)32 * D_MODEL;
    bf16x8 qf0[4], qf1[4];
#pragma unroll
    for (int ks = 0; ks < 4; ++ks) {
        qf0[ks] = *(const bf16x8*)(Qrow0 + ks * 16 + hl * 8);
        qf1[ks] = *(const bf16x8*)(Qrow1 + ks * 16 + hl * 8);
    }

    float l0 = 0.f, l1 = 0.f;
    f32x16 acc00, acc01, acc10, acc11;   // [qsub][nt], named -> always registers
#pragma unroll
    for (int i = 0; i < 16; ++i) {
        acc00[i] = 0.f; acc01[i] = 0.f; acc10[i] = 0.f; acc11[i] = 0.f;
    }

    int kr[2], kc[2], vr[2], vc[2];
#pragma unroll
    for (int it = 0; it < 2; ++it) {
        int c = tid + it * 512;      // 0..1023
        kr[it] = c >> 3;  kc[it] = (c & 7) * 8;    // Ks: 128 rows x 64 d
        vr[it] = c >> 4;  vc[it] = (c & 15) * 8;   // Vs: 64 rows x 128 t
    }
    bf16x8 gk[2], gv[2];
#pragma unroll
    for (int it = 0; it < 2; ++it) {
        gk[it] = *(const bf16x8*)(Kbase + (size_t)kr[it] * D_MODEL + kc[it]);
        gv[it] = *(const bf16x8*)(Vbase + (size_t)vr[it] * SEQ + vc[it]);
    }

    for (int t0 = 0; t0 < SEQ; t0 += 128) {
        __syncthreads();
#pragma unroll
        for (int it = 0; it < 2; ++it) {
            *(bf16x8*)&sm.s.Ks[kr[it]][kc[it]] = gk[it];
            *(bf16x8*)&sm.s.Vs[vr[it]][vc[it]] = gv[it];
        }
        __syncthreads();

        if (t0 + 128 < SEQ) {
#pragma unroll
            for (int it = 0; it < 2; ++it) {
                gk[it] = *(const bf16x8*)(Kbase + (size_t)(t0 + 128 + kr[it]) * D_MODEL + kc[it]);
                gv[it] = *(const bf16x8*)(Vbase + (size_t)vr[it] * SEQ + t0 + 128 + vc[it]);
            }
        }

        // ---- QK^T + softmax for both mt tiles; P frags in registers ----
        // pq{qsub}[ksl]: A-frag covering local key-slice ksl = 2*mt + half.
        u32x4 pq0[4], pq1[4];
#pragma unroll
        for (int mt = 0; mt < 2; ++mt) {
            f32x16 s0, s1;
#pragma unroll
            for (int i = 0; i < 16; ++i) { s0[i] = 0.f; s1[i] = 0.f; }
#pragma unroll
            for (int ks = 0; ks < 4; ++ks) {
                bf16x8 kf = *(const bf16x8*)&sm.s.Ks[kg * 64 + mt * 32 + m32][ks * 16 + hl * 8];
                s0 = MFMA32(kf, qf0[ks], s0);
                s1 = MFMA32(kf, qf1[ks], s1);
            }
            u32x4 a0, b0, a1, b1;
            softmax_pack(s0, l0, a0, b0);
            softmax_pack(s1, l1, a1, b1);
            pq0[2 * mt] = a0; pq0[2 * mt + 1] = b0;
            pq1[2 * mt] = a1; pq1[2 * mt + 1] = b1;
        }

        // ---- O += P V: each va read feeds both q-subtiles ----
#pragma unroll
        for (int ksl = 0; ksl < 4; ++ksl) {
            bf16x8 pA = __builtin_bit_cast(bf16x8, pq0[ksl]);
            bf16x8 pB = __builtin_bit_cast(bf16x8, pq1[ksl]);
            bf16x8 v0 = *(const bf16x8*)&sm.s.Vs[0 * 32 + m32][kg * 64 + ksl * 16 + hl * 8];
            acc00 = MFMA32(pA, v0, acc00);
            acc10 = MFMA32(pB, v0, acc10);
            bf16x8 v1 = *(const bf16x8*)&sm.s.Vs[1 * 32 + m32][kg * 64 + ksl * 16 + hl * 8];
            acc01 = MFMA32(pA, v1, acc01);
            acc11 = MFMA32(pB, v1, acc11);
        }
    }

    // ---- combine key-halves + normalize + store (two rounds, reuse Obuf) ----
    l0 += __shfl_xor(l0, 32);
    l1 += __shfl_xor(l1, 32);

#pragma unroll
    for (int qs = 0; qs < 2; ++qs) {
        float l = (qs == 0) ? l0 : l1;
        __syncthreads();                     // Ks/Vs (or prev Obuf round) dead
        if (kg == 1) {
#pragma unroll
            for (int r = 0; r < 16; ++r) {
                int qq = (r & 3) + 8 * (r >> 2) + 4 * hl;
                sm.Obuf[qg][qq][0 * 32 + m32] = (qs == 0) ? acc00[r] : acc10[r];
                sm.Obuf[qg][qq][1 * 32 + m32] = (qs == 0) ? acc01[r] : acc11[r];
            }
            if (hl == 0) Lbuf[qg][m32] = l;
        }
        __syncthreads();
        if (kg == 0) {
            float lt  = l + Lbuf[qg][m32];
            float inv = 1.0f / lt;           // valid for q = m32
#pragma unroll
            for (int r = 0; r < 16; ++r) {
                int qq = (r & 3) + 8 * (r >> 2) + 4 * hl;
                float v0 = ((qs == 0) ? acc00[r] : acc10[r]) + sm.Obuf[qg][qq][0 * 32 + m32];
                float v1 = ((qs == 0) ? acc01[r] : acc11[r]) + sm.Obuf[qg][qq][1 * 32 + m32];
                float iv = __shfl(inv, qq);
                size_t row = (size_t)(b * SEQ + q0 + qg * 64 + qs * 32 + qq);
                O[row * D_MODEL + h * DK + 0 * 32 + m32] = (bf16)(v0 * iv);
                O[row * D_MODEL + h * DK + 1 * 32 + m32] = (bf16)(v1 * iv);
            }
        }
    }
}

// ---------------------------------------------------------------------------
// Kernel 3: output projection, 64x64 tile (1024 blocks -> 4/CU), bf16 W.
// ---------------------------------------------------------------------------
__global__ __launch_bounds__(256, 4) void proj_out(
    const bf16* __restrict__ Oin, const bf16* __restrict__ Wo,
    const float* __restrict__ bo, float* __restrict__ out)
{
    __shared__ bf16 As[64][72];
    __shared__ bf16 Bs[64][72];

    const int m0   = blockIdx.x * 64;
    const int n0   = blockIdx.y * 64;
    const int tid  = threadIdx.x;
    const int lane = tid & 63;
    const int wave = tid >> 6;
    const int low4 = lane & 15;
    const int quad = lane >> 4;
    const int wm   = wave >> 1;
    const int wn   = wave & 1;

    int arow[2], ag[2];
    for (int it = 0; it < 2; ++it) {
        int idx = tid + it * 256;
        arow[it] = idx >> 3;
        ag[it]   = (idx & 7) * 8;
    }

    bf16x8 gA[2], gB[2];
    for (int it = 0; it < 2; ++it) {
        gA[it] = *(const bf16x8*)(Oin + (size_t)(m0 + arow[it]) * D_MODEL + ag[it]);
        gB[it] = *(const bf16x8*)(Wo + (size_t)(n0 + arow[it]) * D_MODEL + ag[it]);
    }

    f32x4 acc[2][2];
    for (int i = 0; i < 2; ++i)
        for (int j = 0; j < 2; ++j)
            acc[i][j] = f32x4{0.f, 0.f, 0.f, 0.f};

    for (int k0 = 0; k0 < D_MODEL; k0 += 64) {
        __syncthreads();
        for (int it = 0; it < 2; ++it) {
            *(bf16x8*)&As[arow[it]][ag[it]] = gA[it];
            *(bf16x8*)&Bs[arow[it]][ag[it]] = gB[it];
        }
        __syncthreads();

        if (k0 + 64 < D_MODEL) {
            for (int it = 0; it < 2; ++it) {
                gA[it] = *(const bf16x8*)(Oin + (size_t)(m0 + arow[it]) * D_MODEL + k0 + 64 + ag[it]);
                gB[it] = *(const bf16x8*)(Wo + (size_t)(n0 + arow[it]) * D_MODEL + k0 + 64 + ag[it]);
            }
        }

        for (int ks = 0; ks < 2; ++ks) {
            bf16x8 a[2], b[2];
            for (int i = 0; i < 2; ++i)
                a[i] = *(const bf16x8*)&As[wm * 32 + i * 16 + low4][ks * 32 + quad * 8];
            for (int j = 0; j < 2; ++j)
                b[j] = *(const bf16x8*)&Bs[wn * 32 + j * 16 + low4][ks * 32 + quad * 8];
            for (int i = 0; i < 2; ++i)
                for (int j = 0; j < 2; ++j)
                    acc[i][j] = MFMA16(a[i], b[j], acc[i][j]);
        }
    }

    for (int j = 0; j < 2; ++j) {
        int col = n0 + wn * 32 + j * 16 + low4;
        float bcol = bo[col];
        for (int i = 0; i < 2; ++i)
            for (int r = 0; r < 4; ++r) {
                int row = m0 + wm * 32 + i * 16 + quad * 4 + r;
                out[(size_t)row * D_MODEL + col] = acc[i][j][r] + bcol;
            }
    }
}

// ---------------------------------------------------------------------------
extern "C" void kernel_launch(void* const* d_in, const int* in_sizes, int n_in,
                              void* d_out, int out_size, void* d_ws, size_t ws_size,
                              hipStream_t stream)
{
    const float* q  = (const float*)d_in[0];
    const float* k  = (const float*)d_in[1];
    const float* v  = (const float*)d_in[2];
    const float* wq = (const float*)d_in[3];
    const float* bq = (const float*)d_in[4];
    const float* wk = (const float*)d_in[5];
    const float* bk = (const float*)d_in[6];
    const float* wv = (const float*)d_in[7];
    const float* bv = (const float*)d_in[8];
    const float* wo = (const float*)d_in[9];
    const float* bo = (const float*)d_in[10];

    const size_t NT = (size_t)NTOK * D_MODEL;
    bf16* Qh = (bf16*)d_ws;
    bf16* Kh = Qh + NT;
    bf16* Vt = Kh + NT;
    bf16* O  = Vt + NT;
    bf16* Wb = O + NT;                   // 4 x 512 x 512 bf16 = 2 MB

    cvt_w<<<1024, 256, 0, stream>>>(wq, wk, wv, wo, Wb);

    dim3 g1(NTOK / 128, D_MODEL / 128, 3);
    proj_qkv<<<g1, 256, 0, stream>>>(q, k, v, Wb, bq, bk, bv, Qh, Kh, Vt);

    dim3 g2(SEQ / 256, BATCH * NHEAD);
    attn<<<g2, 512, 0, stream>>>(Qh, Kh, Vt, O);

    dim3 g3(NTOK / 64, D_MODEL / 64);
    proj_out<<<g3, 256, 0, stream>>>(O, Wb + (size_t)3 * D_MODEL * D_MODEL, bo, (float*)d_out);
}